// Round 23
// baseline (139.179 us; speedup 1.0000x reference)
//
#include <hip/hip_runtime.h>

#define NB 4
#define LQ 512
#define LK 512
#define EE 128
#define DD 256

__device__ __forceinline__ float fast_rcp(float x) { return __builtin_amdgcn_rcpf(x); }

// K1: R10-proven: 4 rows/block, 1024 blocks -> 4 blocks/CU, 4 waves/SIMD.
__global__ __launch_bounds__(256) void proj_exp_kernel(
    const float* __restrict__ query, const float* __restrict__ key,
    const float* __restrict__ Wc1, const float* __restrict__ Wc2,
    float* __restrict__ EqT, float* __restrict__ Ek)
{
    __shared__ float in_s[4][DD];   // 4 KB
    const int r0 = blockIdx.x * 4;
    const bool is_q = (r0 < NB * LQ);
    const float* src = is_q ? query : key;
    const float* W   = is_q ? Wc1   : Wc2;
    const int rbase  = is_q ? r0    : r0 - NB * LQ;

    ((float4*)in_s)[threadIdx.x] =
        ((const float4*)(src + (size_t)rbase * DD))[threadIdx.x];
    __syncthreads();

    const int c  = threadIdx.x & 127;
    const int rg = threadIdx.x >> 7;
    float acc[2] = {0.f, 0.f};
    for (int d = 0; d < DD; d += 8) {
        const float w0 = W[(d + 0) * EE + c];
        const float w1 = W[(d + 1) * EE + c];
        const float w2 = W[(d + 2) * EE + c];
        const float w3 = W[(d + 3) * EE + c];
        const float w4 = W[(d + 4) * EE + c];
        const float w5 = W[(d + 5) * EE + c];
        const float w6 = W[(d + 6) * EE + c];
        const float w7 = W[(d + 7) * EE + c];
        #pragma unroll
        for (int i = 0; i < 2; ++i) {
            const float4 xa = *(const float4*)&in_s[rg * 2 + i][d];
            const float4 xb = *(const float4*)&in_s[rg * 2 + i][d + 4];
            acc[i] += xa.x * w0 + xa.y * w1 + xa.z * w2 + xa.w * w3
                    + xb.x * w4 + xb.y * w5 + xb.z * w6 + xb.w * w7;
        }
    }
    if (is_q) {
        const int b    = rbase >> 9;
        const int qloc = (rbase & 511) + rg * 2;
        float2 o;
        o.x = __expf(2.0f * acc[0]);
        o.y = __expf(2.0f * acc[1]);
        *(float2*)&EqT[((size_t)(b * EE + c)) * LQ + qloc] = o;
    } else {
        #pragma unroll
        for (int i = 0; i < 2; ++i)
            Ek[(size_t)(rbase + rg * 2 + i) * EE + c] = __expf(2.0f * acc[i]);
    }
}

// K2: R22 experiment (queued since R17, best config now double-banked):
// __launch_bounds__(512, 6) targets 6 waves/SIMD (3 blocks/CU, VGPR ~85)
// + unroll 2 (was 4) halves live prefetch state so the budget fits without
// scratch. R13 probe: VALUBusy 69% / 31% idle at 4 waves/SIMD, VGPR=128.
// VALU-busy TIME (14.6us) is shape-invariant -> extra waves convert idle
// into elapsed reduction. Shape (4-row/512thr) proven optimal (R11/R14).
// Accumulation order unchanged -> bit-identical output.
__global__ __launch_bounds__(512, 6) void atten_kernel(
    const float* __restrict__ EqT, const float* __restrict__ Ek,
    const float* __restrict__ vc, float* __restrict__ attn)
{
    __shared__ float  ek_s[4][EE];      // 2 KB
    __shared__ float  vc_s[EE];         // 0.5 KB
    __shared__ float  s2p_s[4][4][LQ];  // 32 KB
    __shared__ float  sj_s[4][LQ];      // 8 KB
    __shared__ float2 mZ_s[4][2];
    __shared__ float  scale_s[4][2];
    const int b   = blockIdx.x >> 7;
    const int lt  = blockIdx.x & 127;
    const int l0  = lt * 4;
    const int tid = threadIdx.x;
    const int qq  = tid & 127;          // q-quad
    const int eg  = tid >> 7;           // e-group

    ((float*)ek_s)[tid] = Ek[((size_t)b * LK + l0) * EE + tid];   // coalesced
    if (tid < EE) vc_s[tid] = vc[tid];
    __syncthreads();

    float vcsum = 0.f;
    #pragma unroll
    for (int e = 0; e < EE; e += 4) {
        const float4 v = *(const float4*)&vc_s[e];
        vcsum += (v.x + v.y) + (v.z + v.w);
    }

    const float4* eq4 = (const float4*)(EqT + (size_t)b * EE * LQ);
    float s2[4][4];
    #pragma unroll
    for (int l = 0; l < 4; ++l) { s2[l][0]=0.f; s2[l][1]=0.f; s2[l][2]=0.f; s2[l][3]=0.f; }

    #pragma unroll 2
    for (int i = 0; i < 32; ++i) {
        const int e = eg * 32 + i;
        const float4 a  = eq4[(size_t)e * 128 + qq];   // coalesced float4
        const float  vv = vc_s[e];                     // broadcast
        #pragma unroll
        for (int l = 0; l < 4; ++l) {
            const float kk = ek_s[l][e];               // broadcast
            s2[l][0] += vv * fast_rcp(a.x * kk + 1.0f);
            s2[l][1] += vv * fast_rcp(a.y * kk + 1.0f);
            s2[l][2] += vv * fast_rcp(a.z * kk + 1.0f);
            s2[l][3] += vv * fast_rcp(a.w * kk + 1.0f);
        }
    }

    #pragma unroll
    for (int l = 0; l < 4; ++l)
        *(float4*)&s2p_s[eg][l][qq * 4] =
            make_float4(s2[l][0], s2[l][1], s2[l][2], s2[l][3]);
    __syncthreads();

    const int w = tid >> 6, lane = tid & 63;
    const int l = w & 3, h2 = w >> 2, base = h2 * 256;
    float sjv[4];
    float m = -1e30f;
    #pragma unroll
    for (int i = 0; i < 4; ++i) {
        const int idx = base + lane + 64 * i;
        const float p = s2p_s[0][l][idx] + s2p_s[1][l][idx]
                      + s2p_s[2][l][idx] + s2p_s[3][l][idx];
        sjv[i] = vcsum - 2.0f * p;
        m = fmaxf(m, sjv[i]);
    }
    #pragma unroll
    for (int off = 32; off >= 1; off >>= 1) m = fmaxf(m, __shfl_xor(m, off));
    float Z = 0.f;
    #pragma unroll
    for (int i = 0; i < 4; ++i) {
        const int idx = base + lane + 64 * i;
        const float ex = __expf(sjv[i] - m);
        sj_s[l][idx] = ex;                                    // lane-exclusive
        Z += ex;
    }
    #pragma unroll
    for (int off = 32; off >= 1; off >>= 1) Z += __shfl_xor(Z, off);
    if (lane == 0) mZ_s[l][h2] = make_float2(m, Z);
    __syncthreads();
    if (lane == 0) {
        const float2 A = mZ_s[l][0], B2 = mZ_s[l][1];
        const float M  = fmaxf(A.x, B2.x);
        const float Zt = A.y * __expf(A.x - M) + B2.y * __expf(B2.x - M);
        scale_s[l][h2] = __expf((h2 ? B2.x : A.x) - M) * fast_rcp(Zt);
    }
    __syncthreads();

    const int q = tid;
    #pragma unroll
    for (int li = 0; li < 4; ++li)
        attn[(size_t)(b * LK + l0 + li) * LQ + q] = sj_s[li][q] * scale_s[li][q >> 8];
}

// K3: R8-proven version (256 blocks x 1024 thr, 8 rows, 16 groups,
// attn tile in LDS + value loads pipelined one step ahead).
__global__ __launch_bounds__(1024) void context_kernel(
    const float* __restrict__ attn, const float* __restrict__ value,
    float* __restrict__ ctx)
{
    const int b    = blockIdx.x >> 6;
    const int lt   = blockIdx.x & 63;
    const int row0 = b * LK + lt * 8;
    const int tid  = threadIdx.x;
    const int g    = tid >> 6;
    const int lane = tid & 63;
    const float4* v4 = (const float4*)(value + (size_t)b * LQ * DD);

    __shared__ float  s_attn[8][LQ];   // 16 KB
    __shared__ float4 red[8][8][64];   // 64 KB

    {
        const int r  = tid >> 7;
        const int c4 = tid & 127;
        *(float4*)&s_attn[r][c4 * 4] =
            *(const float4*)(attn + (size_t)(row0 + r) * LQ + c4 * 4);
    }
    __syncthreads();

    float4 ac[8];
    #pragma unroll
    for (int l = 0; l < 8; ++l) ac[l] = make_float4(0.f, 0.f, 0.f, 0.f);

    const int q0 = g * 32;
    float4 v0 = v4[(size_t)(q0 + 0) * 64 + lane];
    float4 v1 = v4[(size_t)(q0 + 1) * 64 + lane];
    float4 v2 = v4[(size_t)(q0 + 2) * 64 + lane];
    float4 v3 = v4[(size_t)(q0 + 3) * 64 + lane];
    #pragma unroll
    for (int qs = 0; qs < 8; ++qs) {
        const int q = q0 + qs * 4;
        float4 n0, n1, n2, n3;
        if (qs < 7) {
            n0 = v4[(size_t)(q + 4) * 64 + lane];
            n1 = v4[(size_t)(q + 5) * 64 + lane];
            n2 = v4[(size_t)(q + 6) * 64 + lane];
            n3 = v4[(size_t)(q + 7) * 64 + lane];
        }
        float4 a[8];
        #pragma unroll
        for (int l = 0; l < 8; ++l)
            a[l] = *(const float4*)&s_attn[l][q];
        #pragma unroll
        for (int l = 0; l < 8; ++l) {
            ac[l].x += a[l].x * v0.x; ac[l].y += a[l].x * v0.y;
            ac[l].z += a[l].x * v0.z; ac[l].w += a[l].x * v0.w;
            ac[l].x += a[l].y * v1.x; ac[l].y += a[l].y * v1.y;
            ac[l].z += a[l].y * v1.z; ac[l].w += a[l].y * v1.w;
            ac[l].x += a[l].z * v2.x; ac[l].y += a[l].z * v2.y;
            ac[l].z += a[l].z * v2.z; ac[l].w += a[l].z * v2.w;
            ac[l].x += a[l].w * v3.x; ac[l].y += a[l].w * v3.y;
            ac[l].z += a[l].w * v3.z; ac[l].w += a[l].w * v3.w;
        }
        if (qs < 7) { v0 = n0; v1 = n1; v2 = n2; v3 = n3; }
    }

    if (g >= 8) {
        #pragma unroll
        for (int l = 0; l < 8; ++l) red[g - 8][l][lane] = ac[l];
    }
    __syncthreads();
    if (g < 8) {
        #pragma unroll
        for (int l = 0; l < 8; ++l) {
            const float4 r = red[g][l][lane];
            ac[l].x += r.x; ac[l].y += r.y; ac[l].z += r.z; ac[l].w += r.w;
        }
    }
    __syncthreads();
    if (g >= 4 && g < 8) {
        #pragma unroll
        for (int l = 0; l < 8; ++l) red[g - 4][l][lane] = ac[l];
    }
    __syncthreads();
    if (g < 4) {
        #pragma unroll
        for (int l = 0; l < 8; ++l) {
            const float4 r = red[g][l][lane];
            ac[l].x += r.x; ac[l].y += r.y; ac[l].z += r.z; ac[l].w += r.w;
        }
    }
    __syncthreads();
    if (g == 2 || g == 3) {
        #pragma unroll
        for (int l = 0; l < 8; ++l) red[g - 2][l][lane] = ac[l];
    }
    __syncthreads();
    if (g < 2) {
        #pragma unroll
        for (int l = 0; l < 8; ++l) {
            const float4 r = red[g][l][lane];
            ac[l].x += r.x; ac[l].y += r.y; ac[l].z += r.z; ac[l].w += r.w;
        }
    }
    __syncthreads();
    if (g == 1) {
        #pragma unroll
        for (int l = 0; l < 8; ++l) red[0][l][lane] = ac[l];
    }
    __syncthreads();
    if (g == 0) {
        #pragma unroll
        for (int l = 0; l < 8; ++l) {
            const float4 r = red[0][l][lane];
            ac[l].x += r.x; ac[l].y += r.y; ac[l].z += r.z; ac[l].w += r.w;
            ((float4*)ctx)[(size_t)(row0 + l) * 64 + lane] = ac[l];
        }
    }
}

extern "C" void kernel_launch(void* const* d_in, const int* in_sizes, int n_in,
                              void* d_out, int out_size, void* d_ws, size_t ws_size,
                              hipStream_t stream) {
    const float* query = (const float*)d_in[0];
    const float* key   = (const float*)d_in[1];
    const float* value = (const float*)d_in[2];
    const float* Wc1   = (const float*)d_in[3];
    const float* Wc2   = (const float*)d_in[4];
    const float* vc    = (const float*)d_in[5];

    float* ctx  = (float*)d_out;                          // [B, Lk, D]
    float* attn = (float*)d_out + (size_t)NB * LK * DD;   // [B, Lk, Lq]

    // Scratch aliases ctx region; safe ONLY because of kernel boundaries
    // (K2 fully drains before K3 overwrites). d_ws is NOT used (re-poison
    // race, prior session); grid barriers falsified (R3: 240us).
    float* EqT = ctx;                                     // [B, E, Lq]
    float* Ek  = ctx + (size_t)NB * LQ * EE;              // [B, Lk, E]

    proj_exp_kernel<<<dim3(1024), dim3(256), 0, stream>>>(query, key, Wc1, Wc2, EqT, Ek);
    atten_kernel<<<dim3(NB * (LK / 4)), dim3(512), 0, stream>>>(EqT, Ek, vc, attn);
    context_kernel<<<dim3(NB * (LK / 8)), dim3(1024), 0, stream>>>(attn, value, ctx);
}

// Round 25
// 116.165 us; speedup vs baseline: 1.1981x; 1.1981x over previous
//
#include <hip/hip_runtime.h>

#define NB 4
#define LQ 512
#define LK 512
#define EE 128
#define DD 256

__device__ __forceinline__ float fast_rcp(float x) { return __builtin_amdgcn_rcpf(x); }

// K1: R10-proven: 4 rows/block, 1024 blocks -> 4 blocks/CU, 4 waves/SIMD.
__global__ __launch_bounds__(256) void proj_exp_kernel(
    const float* __restrict__ query, const float* __restrict__ key,
    const float* __restrict__ Wc1, const float* __restrict__ Wc2,
    float* __restrict__ EqT, float* __restrict__ Ek)
{
    __shared__ float in_s[4][DD];   // 4 KB
    const int r0 = blockIdx.x * 4;
    const bool is_q = (r0 < NB * LQ);
    const float* src = is_q ? query : key;
    const float* W   = is_q ? Wc1   : Wc2;
    const int rbase  = is_q ? r0    : r0 - NB * LQ;

    ((float4*)in_s)[threadIdx.x] =
        ((const float4*)(src + (size_t)rbase * DD))[threadIdx.x];
    __syncthreads();

    const int c  = threadIdx.x & 127;
    const int rg = threadIdx.x >> 7;
    float acc[2] = {0.f, 0.f};
    for (int d = 0; d < DD; d += 8) {
        const float w0 = W[(d + 0) * EE + c];
        const float w1 = W[(d + 1) * EE + c];
        const float w2 = W[(d + 2) * EE + c];
        const float w3 = W[(d + 3) * EE + c];
        const float w4 = W[(d + 4) * EE + c];
        const float w5 = W[(d + 5) * EE + c];
        const float w6 = W[(d + 6) * EE + c];
        const float w7 = W[(d + 7) * EE + c];
        #pragma unroll
        for (int i = 0; i < 2; ++i) {
            const float4 xa = *(const float4*)&in_s[rg * 2 + i][d];
            const float4 xb = *(const float4*)&in_s[rg * 2 + i][d + 4];
            acc[i] += xa.x * w0 + xa.y * w1 + xa.z * w2 + xa.w * w3
                    + xb.x * w4 + xb.y * w5 + xb.z * w6 + xb.w * w7;
        }
    }
    if (is_q) {
        const int b    = rbase >> 9;
        const int qloc = (rbase & 511) + rg * 2;
        float2 o;
        o.x = __expf(2.0f * acc[0]);
        o.y = __expf(2.0f * acc[1]);
        *(float2*)&EqT[((size_t)(b * EE + c)) * LQ + qloc] = o;
    } else {
        #pragma unroll
        for (int i = 0; i < 2; ++i)
            Ek[(size_t)(rbase + rg * 2 + i) * EE + c] = __expf(2.0f * acc[i]);
    }
}

// K2: FINAL — proven 4-row/512-thr version (R2/R8/R10; ~21.3us, VALUBusy 69%,
// VGPR 128, 4 waves/SIMD). This shape is a measured local optimum; all three
// occupancy levers falsified: R11 wider block -> spill (VGPR=64, 176MB
// scratch); R14 thinner block -> starved (54us); R22 launch_bounds(512,6)
// register cap -> spill (VGPR=40, 150MB scratch, 45us). The compiler's
// uncapped allocation is the balanced optimum. Do NOT cap this kernel.
__global__ __launch_bounds__(512) void atten_kernel(
    const float* __restrict__ EqT, const float* __restrict__ Ek,
    const float* __restrict__ vc, float* __restrict__ attn)
{
    __shared__ float  ek_s[4][EE];      // 2 KB
    __shared__ float  vc_s[EE];         // 0.5 KB
    __shared__ float  s2p_s[4][4][LQ];  // 32 KB
    __shared__ float  sj_s[4][LQ];      // 8 KB
    __shared__ float2 mZ_s[4][2];
    __shared__ float  scale_s[4][2];
    const int b   = blockIdx.x >> 7;
    const int lt  = blockIdx.x & 127;
    const int l0  = lt * 4;
    const int tid = threadIdx.x;
    const int qq  = tid & 127;          // q-quad
    const int eg  = tid >> 7;           // e-group

    ((float*)ek_s)[tid] = Ek[((size_t)b * LK + l0) * EE + tid];   // coalesced
    if (tid < EE) vc_s[tid] = vc[tid];
    __syncthreads();

    float vcsum = 0.f;
    #pragma unroll
    for (int e = 0; e < EE; e += 4) {
        const float4 v = *(const float4*)&vc_s[e];
        vcsum += (v.x + v.y) + (v.z + v.w);
    }

    const float4* eq4 = (const float4*)(EqT + (size_t)b * EE * LQ);
    float s2[4][4];
    #pragma unroll
    for (int l = 0; l < 4; ++l) { s2[l][0]=0.f; s2[l][1]=0.f; s2[l][2]=0.f; s2[l][3]=0.f; }

    #pragma unroll 4
    for (int i = 0; i < 32; ++i) {
        const int e = eg * 32 + i;
        const float4 a  = eq4[(size_t)e * 128 + qq];   // coalesced float4
        const float  vv = vc_s[e];                     // broadcast
        #pragma unroll
        for (int l = 0; l < 4; ++l) {
            const float kk = ek_s[l][e];               // broadcast
            s2[l][0] += vv * fast_rcp(a.x * kk + 1.0f);
            s2[l][1] += vv * fast_rcp(a.y * kk + 1.0f);
            s2[l][2] += vv * fast_rcp(a.z * kk + 1.0f);
            s2[l][3] += vv * fast_rcp(a.w * kk + 1.0f);
        }
    }

    #pragma unroll
    for (int l = 0; l < 4; ++l)
        *(float4*)&s2p_s[eg][l][qq * 4] =
            make_float4(s2[l][0], s2[l][1], s2[l][2], s2[l][3]);
    __syncthreads();

    const int w = tid >> 6, lane = tid & 63;
    const int l = w & 3, h2 = w >> 2, base = h2 * 256;
    float sjv[4];
    float m = -1e30f;
    #pragma unroll
    for (int i = 0; i < 4; ++i) {
        const int idx = base + lane + 64 * i;
        const float p = s2p_s[0][l][idx] + s2p_s[1][l][idx]
                      + s2p_s[2][l][idx] + s2p_s[3][l][idx];
        sjv[i] = vcsum - 2.0f * p;
        m = fmaxf(m, sjv[i]);
    }
    #pragma unroll
    for (int off = 32; off >= 1; off >>= 1) m = fmaxf(m, __shfl_xor(m, off));
    float Z = 0.f;
    #pragma unroll
    for (int i = 0; i < 4; ++i) {
        const int idx = base + lane + 64 * i;
        const float ex = __expf(sjv[i] - m);
        sj_s[l][idx] = ex;                                    // lane-exclusive
        Z += ex;
    }
    #pragma unroll
    for (int off = 32; off >= 1; off >>= 1) Z += __shfl_xor(Z, off);
    if (lane == 0) mZ_s[l][h2] = make_float2(m, Z);
    __syncthreads();
    if (lane == 0) {
        const float2 A = mZ_s[l][0], B2 = mZ_s[l][1];
        const float M  = fmaxf(A.x, B2.x);
        const float Zt = A.y * __expf(A.x - M) + B2.y * __expf(B2.x - M);
        scale_s[l][h2] = __expf((h2 ? B2.x : A.x) - M) * fast_rcp(Zt);
    }
    __syncthreads();

    const int q = tid;
    #pragma unroll
    for (int li = 0; li < 4; ++li)
        attn[(size_t)(b * LK + l0 + li) * LQ + q] = sj_s[li][q] * scale_s[li][q >> 8];
}

// K3: R8-proven version (256 blocks x 1024 thr, 8 rows, 16 groups,
// attn tile in LDS + value loads pipelined one step ahead).
__global__ __launch_bounds__(1024) void context_kernel(
    const float* __restrict__ attn, const float* __restrict__ value,
    float* __restrict__ ctx)
{
    const int b    = blockIdx.x >> 6;
    const int lt   = blockIdx.x & 63;
    const int row0 = b * LK + lt * 8;
    const int tid  = threadIdx.x;
    const int g    = tid >> 6;
    const int lane = tid & 63;
    const float4* v4 = (const float4*)(value + (size_t)b * LQ * DD);

    __shared__ float  s_attn[8][LQ];   // 16 KB
    __shared__ float4 red[8][8][64];   // 64 KB

    {
        const int r  = tid >> 7;
        const int c4 = tid & 127;
        *(float4*)&s_attn[r][c4 * 4] =
            *(const float4*)(attn + (size_t)(row0 + r) * LQ + c4 * 4);
    }
    __syncthreads();

    float4 ac[8];
    #pragma unroll
    for (int l = 0; l < 8; ++l) ac[l] = make_float4(0.f, 0.f, 0.f, 0.f);

    const int q0 = g * 32;
    float4 v0 = v4[(size_t)(q0 + 0) * 64 + lane];
    float4 v1 = v4[(size_t)(q0 + 1) * 64 + lane];
    float4 v2 = v4[(size_t)(q0 + 2) * 64 + lane];
    float4 v3 = v4[(size_t)(q0 + 3) * 64 + lane];
    #pragma unroll
    for (int qs = 0; qs < 8; ++qs) {
        const int q = q0 + qs * 4;
        float4 n0, n1, n2, n3;
        if (qs < 7) {
            n0 = v4[(size_t)(q + 4) * 64 + lane];
            n1 = v4[(size_t)(q + 5) * 64 + lane];
            n2 = v4[(size_t)(q + 6) * 64 + lane];
            n3 = v4[(size_t)(q + 7) * 64 + lane];
        }
        float4 a[8];
        #pragma unroll
        for (int l = 0; l < 8; ++l)
            a[l] = *(const float4*)&s_attn[l][q];
        #pragma unroll
        for (int l = 0; l < 8; ++l) {
            ac[l].x += a[l].x * v0.x; ac[l].y += a[l].x * v0.y;
            ac[l].z += a[l].x * v0.z; ac[l].w += a[l].x * v0.w;
            ac[l].x += a[l].y * v1.x; ac[l].y += a[l].y * v1.y;
            ac[l].z += a[l].y * v1.z; ac[l].w += a[l].y * v1.w;
            ac[l].x += a[l].z * v2.x; ac[l].y += a[l].z * v2.y;
            ac[l].z += a[l].z * v2.z; ac[l].w += a[l].z * v2.w;
            ac[l].x += a[l].w * v3.x; ac[l].y += a[l].w * v3.y;
            ac[l].z += a[l].w * v3.z; ac[l].w += a[l].w * v3.w;
        }
        if (qs < 7) { v0 = n0; v1 = n1; v2 = n2; v3 = n3; }
    }

    if (g >= 8) {
        #pragma unroll
        for (int l = 0; l < 8; ++l) red[g - 8][l][lane] = ac[l];
    }
    __syncthreads();
    if (g < 8) {
        #pragma unroll
        for (int l = 0; l < 8; ++l) {
            const float4 r = red[g][l][lane];
            ac[l].x += r.x; ac[l].y += r.y; ac[l].z += r.z; ac[l].w += r.w;
        }
    }
    __syncthreads();
    if (g >= 4 && g < 8) {
        #pragma unroll
        for (int l = 0; l < 8; ++l) red[g - 4][l][lane] = ac[l];
    }
    __syncthreads();
    if (g < 4) {
        #pragma unroll
        for (int l = 0; l < 8; ++l) {
            const float4 r = red[g][l][lane];
            ac[l].x += r.x; ac[l].y += r.y; ac[l].z += r.z; ac[l].w += r.w;
        }
    }
    __syncthreads();
    if (g == 2 || g == 3) {
        #pragma unroll
        for (int l = 0; l < 8; ++l) red[g - 2][l][lane] = ac[l];
    }
    __syncthreads();
    if (g < 2) {
        #pragma unroll
        for (int l = 0; l < 8; ++l) {
            const float4 r = red[g][l][lane];
            ac[l].x += r.x; ac[l].y += r.y; ac[l].z += r.z; ac[l].w += r.w;
        }
    }
    __syncthreads();
    if (g == 1) {
        #pragma unroll
        for (int l = 0; l < 8; ++l) red[0][l][lane] = ac[l];
    }
    __syncthreads();
    if (g == 0) {
        #pragma unroll
        for (int l = 0; l < 8; ++l) {
            const float4 r = red[0][l][lane];
            ac[l].x += r.x; ac[l].y += r.y; ac[l].z += r.z; ac[l].w += r.w;
            ((float4*)ctx)[(size_t)(row0 + l) * 64 + lane] = ac[l];
        }
    }
}

extern "C" void kernel_launch(void* const* d_in, const int* in_sizes, int n_in,
                              void* d_out, int out_size, void* d_ws, size_t ws_size,
                              hipStream_t stream) {
    const float* query = (const float*)d_in[0];
    const float* key   = (const float*)d_in[1];
    const float* value = (const float*)d_in[2];
    const float* Wc1   = (const float*)d_in[3];
    const float* Wc2   = (const float*)d_in[4];
    const float* vc    = (const float*)d_in[5];

    float* ctx  = (float*)d_out;                          // [B, Lk, D]
    float* attn = (float*)d_out + (size_t)NB * LK * DD;   // [B, Lk, Lq]

    // Scratch aliases ctx region; safe ONLY because of kernel boundaries
    // (K2 fully drains before K3 overwrites). d_ws is NOT used (re-poison
    // race, prior session); grid barriers falsified (R3: 240us).
    float* EqT = ctx;                                     // [B, E, Lq]
    float* Ek  = ctx + (size_t)NB * LQ * EE;              // [B, Lk, E]

    proj_exp_kernel<<<dim3(1024), dim3(256), 0, stream>>>(query, key, Wc1, Wc2, EqT, Ek);
    atten_kernel<<<dim3(NB * (LK / 4)), dim3(512), 0, stream>>>(EqT, Ek, vc, attn);
    context_kernel<<<dim3(NB * (LK / 8)), dim3(1024), 0, stream>>>(attn, value, ctx);
}